// Round 2
// baseline (184.427 us; speedup 1.0000x reference)
//
#include <hip/hip_runtime.h>
#include <hip/hip_bf16.h>
#include <stdint.h>

// FlexHNN fused forward, MI355X gfx950.
// N=131072 rows, DZ=16, H=256. All inputs fp32; compute via bf16 MFMA (fp32 acc).
//
// ws layout (bf16 elements, unsigned short):
//   [0,      8192)  w1h: hW1 padded [256][32] (cols 16..31 zero)
//   [8192,  16384)  w1f: fW1 padded [256][32]
//   [16384, 81920)  w2h: hW2 [256][256]
//   [81920,147456)  w2f: fW2 [256][256]
//   [147456,151552) w3f: fW3 [16][256]
// total 151552 elems = 303104 bytes of d_ws.

typedef __attribute__((ext_vector_type(8))) short short8;   // 8 bf16 = 4 VGPRs (MFMA A/B frag)
typedef __attribute__((ext_vector_type(4))) float floatx4;  // MFMA C/D frag

static __device__ __forceinline__ unsigned short f2bf(float x) {
  union { float f; uint32_t u; } v; v.f = x;
  return (unsigned short)((v.u + 0x7FFFu + ((v.u >> 16) & 1u)) >> 16);  // RNE
}
static __device__ __forceinline__ float bf2f(uint32_t bits16) {
  union { uint32_t u; float f; } v; v.u = bits16 << 16;
  return v.f;
}
static __device__ __forceinline__ float unpk(uint32_t p, int hi) {
  return bf2f(hi ? (p >> 16) : (p & 0xffffu));
}
// clamped Pade(7,6) tanh: max err ~7e-4, pure FMA + one v_rcp_f32
static __device__ __forceinline__ float tanh_fast(float x) {
  float cx = fminf(4.0f, fmaxf(-4.0f, x));
  float x2 = cx * cx;
  float num = cx * (135135.0f + x2 * (17325.0f + x2 * (378.0f + x2)));
  float den = 135135.0f + x2 * (62370.0f + x2 * (3150.0f + 28.0f * x2));
  return num * __builtin_amdgcn_rcpf(den);
}

__global__ __launch_bounds__(256) void prep_kernel(
    const float* __restrict__ hW1, const float* __restrict__ hW2,
    const float* __restrict__ fW1, const float* __restrict__ fW2,
    const float* __restrict__ fW3, unsigned short* __restrict__ ws) {
  int i = blockIdx.x * 256 + threadIdx.x;  // grid covers [0, 65536)
  ws[16384 + i] = f2bf(hW2[i]);
  ws[81920 + i] = f2bf(fW2[i]);
  if (i < 8192) {
    int r = i >> 5, c = i & 31;
    unsigned short vh = 0, vf = 0;
    if (c < 16) { vh = f2bf(hW1[r * 16 + c]); vf = f2bf(fW1[r * 16 + c]); }
    ws[i] = vh;
    ws[8192 + i] = vf;
  }
  if (i < 4096) ws[147456 + i] = f2bf(fW3[i]);
}

__global__ __launch_bounds__(256, 2) void flexhnn_kernel(
    const float* __restrict__ z,
    const float* __restrict__ hb1, const float* __restrict__ hb2,
    const float* __restrict__ fb1, const float* __restrict__ fb2,
    const float* __restrict__ fb3,
    const unsigned short* __restrict__ ws,
    float* __restrict__ out) {
  // LDS: z tile (bf16, K padded to 32) + one reused 64x264 activation buffer
  __shared__ __align__(16) unsigned short z_bf[64 * 32];
  __shared__ __align__(16) unsigned short act[64 * 264];  // pad +8 keeps 16B rows

  const int tid = threadIdx.x;
  const int lane = tid & 63;
  const int wave = tid >> 6;
  const int laneCol = lane & 15;   // A-frag row / B-frag col / D col
  const int kg = lane >> 4;        // k-group (8 bf16 each) / D row-group
  const int wc = wave * 64;        // this wave's hidden-col base
  const int row0 = blockIdx.x * 64;

  const unsigned short* w1h = ws;
  const unsigned short* w1f = ws + 8192;
  const unsigned short* w2h = ws + 16384;
  const unsigned short* w2f = ws + 81920;
  const unsigned short* w3f = ws + 147456;

  // ---- phase 0: stage z tile as bf16, zero-pad K 16->32 ----
  {
    int r = tid >> 2;
    int c = (tid & 3) * 4;
    float4 zv = *reinterpret_cast<const float4*>(z + (size_t)(row0 + r) * 16 + c);
    unsigned short* p = &z_bf[r * 32 + c];
    p[0] = f2bf(zv.x); p[1] = f2bf(zv.y); p[2] = f2bf(zv.z); p[3] = f2bf(zv.w);
    unsigned short* q = &z_bf[r * 32 + 16 + c];
    q[0] = 0; q[1] = 0; q[2] = 0; q[3] = 0;
  }
  __syncthreads();

  // biases for this wave's 4 col-frags
  float hb1v[4], hb2v[4], fb1v[4], fb2v[4];
#pragma unroll
  for (int nf = 0; nf < 4; ++nf) {
    int col = wc + nf * 16 + laneCol;
    hb1v[nf] = hb1[col]; hb2v[nf] = hb2[col];
    fb1v[nf] = fb1[col]; fb2v[nf] = fb2[col];
  }

  uint32_t s1p[4][4][2];  // s1 = 1-t1^2, packed bf16 pairs (r0|r1, r2|r3)

  // ---- phase 1: a1 = z @ hW1^T (K=32 padded); t1 -> act, s1 -> regs ----
  {
    short8 az[4];
#pragma unroll
    for (int mf = 0; mf < 4; ++mf)
      az[mf] = *reinterpret_cast<const short8*>(&z_bf[(mf * 16 + laneCol) * 32 + kg * 8]);
#pragma unroll
    for (int nf = 0; nf < 4; ++nf) {
      int col = wc + nf * 16 + laneCol;
      short8 b = *reinterpret_cast<const short8*>(&w1h[col * 32 + kg * 8]);
#pragma unroll
      for (int mf = 0; mf < 4; ++mf) {
        floatx4 c0 = {0.f, 0.f, 0.f, 0.f};
        floatx4 a1 = __builtin_amdgcn_mfma_f32_16x16x32_bf16(az[mf], b, c0, 0, 0, 0);
        unsigned short tb[4], sb[4];
#pragma unroll
        for (int r = 0; r < 4; ++r) {
          float t = tanh_fast(a1[r] + hb1v[nf]);
          tb[r] = f2bf(t);
          sb[r] = f2bf(1.0f - t * t);
        }
        s1p[mf][nf][0] = (uint32_t)sb[0] | ((uint32_t)sb[1] << 16);
        s1p[mf][nf][1] = (uint32_t)sb[2] | ((uint32_t)sb[3] << 16);
#pragma unroll
        for (int r = 0; r < 4; ++r)
          act[(mf * 16 + kg * 4 + r) * 264 + col] = tb[r];
      }
    }
  }
  __syncthreads();  // t1 visible to all waves

  // ---- phase 2: a2 = t1 @ hW2^T (K=256) -> s2 (regs); f1 = z @ fW1^T ----
  uint32_t s2p[4][4][2];
  {
    floatx4 acc[4][4];
#pragma unroll
    for (int mf = 0; mf < 4; ++mf)
#pragma unroll
      for (int nf = 0; nf < 4; ++nf)
        acc[mf][nf] = (floatx4){0.f, 0.f, 0.f, 0.f};
#pragma unroll 2
    for (int ks = 0; ks < 8; ++ks) {
      int k0 = ks * 32;
      short8 a[4], b[4];
#pragma unroll
      for (int mf = 0; mf < 4; ++mf)
        a[mf] = *reinterpret_cast<const short8*>(&act[(mf * 16 + laneCol) * 264 + k0 + kg * 8]);
#pragma unroll
      for (int nf = 0; nf < 4; ++nf)
        b[nf] = *reinterpret_cast<const short8*>(&w2h[(wc + nf * 16 + laneCol) * 256 + k0 + kg * 8]);
#pragma unroll
      for (int mf = 0; mf < 4; ++mf)
#pragma unroll
        for (int nf = 0; nf < 4; ++nf)
          acc[mf][nf] = __builtin_amdgcn_mfma_f32_16x16x32_bf16(a[mf], b[nf], acc[mf][nf], 0, 0, 0);
    }
#pragma unroll
    for (int mf = 0; mf < 4; ++mf)
#pragma unroll
      for (int nf = 0; nf < 4; ++nf) {
        unsigned short sb[4];
#pragma unroll
        for (int r = 0; r < 4; ++r) {
          float t = tanh_fast(acc[mf][nf][r] + hb2v[nf]);
          sb[r] = f2bf(1.0f - t * t);
        }
        s2p[mf][nf][0] = (uint32_t)sb[0] | ((uint32_t)sb[1] << 16);
        s2p[mf][nf][1] = (uint32_t)sb[2] | ((uint32_t)sb[3] << 16);
      }
  }

  // f1 = z @ fW1^T (K=32 padded), keep in regs across the barrier
  floatx4 accf[4][4];
  {
    short8 az[4];
#pragma unroll
    for (int mf = 0; mf < 4; ++mf)
      az[mf] = *reinterpret_cast<const short8*>(&z_bf[(mf * 16 + laneCol) * 32 + kg * 8]);
#pragma unroll
    for (int nf = 0; nf < 4; ++nf) {
      short8 b = *reinterpret_cast<const short8*>(&w1f[(wc + nf * 16 + laneCol) * 32 + kg * 8]);
#pragma unroll
      for (int mf = 0; mf < 4; ++mf) {
        floatx4 c0 = {0.f, 0.f, 0.f, 0.f};
        accf[mf][nf] = __builtin_amdgcn_mfma_f32_16x16x32_bf16(az[mf], b, c0, 0, 0, 0);
      }
    }
  }
  __syncthreads();  // everyone done READING t1 from act

  // fmix = 0.5*f1*s2 + 0.5*tanh(f1) -> act (bf16)
#pragma unroll
  for (int mf = 0; mf < 4; ++mf)
#pragma unroll
    for (int nf = 0; nf < 4; ++nf) {
      int col = wc + nf * 16 + laneCol;
#pragma unroll
      for (int r = 0; r < 4; ++r) {
        float fv = accf[mf][nf][r] + fb1v[nf];
        float s2 = unpk(s2p[mf][nf][r >> 1], r & 1);
        float fm = 0.5f * (fv * s2 + tanh_fast(fv));
        act[(mf * 16 + kg * 4 + r) * 264 + col] = f2bf(fm);
      }
    }
  __syncthreads();  // fmix visible

  // ---- phase 3: f2 = fmix @ fW2^T (K=256); fmix2 = 0.5*f2*s1 + 0.5*tanh(f2) ----
  {
    floatx4 acc[4][4];
#pragma unroll
    for (int mf = 0; mf < 4; ++mf)
#pragma unroll
      for (int nf = 0; nf < 4; ++nf)
        acc[mf][nf] = (floatx4){0.f, 0.f, 0.f, 0.f};
#pragma unroll 2
    for (int ks = 0; ks < 8; ++ks) {
      int k0 = ks * 32;
      short8 a[4], b[4];
#pragma unroll
      for (int mf = 0; mf < 4; ++mf)
        a[mf] = *reinterpret_cast<const short8*>(&act[(mf * 16 + laneCol) * 264 + k0 + kg * 8]);
#pragma unroll
      for (int nf = 0; nf < 4; ++nf)
        b[nf] = *reinterpret_cast<const short8*>(&w2f[(wc + nf * 16 + laneCol) * 256 + k0 + kg * 8]);
#pragma unroll
      for (int mf = 0; mf < 4; ++mf)
#pragma unroll
        for (int nf = 0; nf < 4; ++nf)
          acc[mf][nf] = __builtin_amdgcn_mfma_f32_16x16x32_bf16(a[mf], b[nf], acc[mf][nf], 0, 0, 0);
    }
    __syncthreads();  // everyone done READING fmix from act
#pragma unroll
    for (int mf = 0; mf < 4; ++mf)
#pragma unroll
      for (int nf = 0; nf < 4; ++nf) {
        int col = wc + nf * 16 + laneCol;
#pragma unroll
        for (int r = 0; r < 4; ++r) {
          float fv = acc[mf][nf][r] + fb2v[nf];
          float s1 = unpk(s1p[mf][nf][r >> 1], r & 1);
          float fm = 0.5f * (fv * s1 + tanh_fast(fv));
          act[(mf * 16 + kg * 4 + r) * 264 + col] = f2bf(fm);
        }
      }
  }
  __syncthreads();  // fmix2 visible

  // ---- phase 4: f3 = fmix2 @ fW3^T (K=256, 16 out cols); symplectic write ----
  {
    floatx4 a4 = {0.f, 0.f, 0.f, 0.f};
#pragma unroll 2
    for (int ks = 0; ks < 8; ++ks) {
      int k0 = ks * 32;
      short8 a = *reinterpret_cast<const short8*>(&act[(wave * 16 + laneCol) * 264 + k0 + kg * 8]);
      short8 b = *reinterpret_cast<const short8*>(&w3f[laneCol * 256 + k0 + kg * 8]);
      a4 = __builtin_amdgcn_mfma_f32_16x16x32_bf16(a, b, a4, 0, 0, 0);
    }
    int o = laneCol;
    float bb3 = fb3[o];
    int oc = (o < 8) ? (o + 8) : (o - 8);      // out[:,0:8]=f[:,8:16]; out[:,8:16]=-f[:,0:8]
    float sgn = (o < 8) ? -1.0f : 1.0f;
#pragma unroll
    for (int r = 0; r < 4; ++r) {
      int grow = row0 + wave * 16 + kg * 4 + r;
      out[(size_t)grow * 16 + oc] = sgn * (a4[r] + bb3);
    }
  }
}

extern "C" void kernel_launch(void* const* d_in, const int* in_sizes, int n_in,
                              void* d_out, int out_size, void* d_ws, size_t ws_size,
                              hipStream_t stream) {
  const float* z   = (const float*)d_in[1];
  const float* hW1 = (const float*)d_in[2];
  const float* hb1 = (const float*)d_in[3];
  const float* hW2 = (const float*)d_in[4];
  const float* hb2 = (const float*)d_in[5];
  const float* fW1 = (const float*)d_in[6];
  const float* fb1 = (const float*)d_in[7];
  const float* fW2 = (const float*)d_in[8];
  const float* fb2 = (const float*)d_in[9];
  const float* fW3 = (const float*)d_in[10];
  const float* fb3 = (const float*)d_in[11];
  unsigned short* ws = (unsigned short*)d_ws;
  float* out = (float*)d_out;

  hipLaunchKernelGGL(prep_kernel, dim3(256), dim3(256), 0, stream,
                     hW1, hW2, fW1, fW2, fW3, ws);
  hipLaunchKernelGGL(flexhnn_kernel, dim3(131072 / 64), dim3(256), 0, stream,
                     z, hb1, hb2, fb1, fb2, fb3, (const unsigned short*)ws, out);
}